// Round 1
// baseline (702.786 us; speedup 1.0000x reference)
//
#include <hip/hip_runtime.h>
#include <hip/hip_bf16.h>

#define E_EDGES 393216
#define NRECV   12288
#define DX      128
#define BATCH   2

typedef short bf16x8 __attribute__((ext_vector_type(8)));
typedef float f32x4  __attribute__((ext_vector_type(4)));

__device__ __forceinline__ unsigned short f2bf(float f) {
  union { float f; unsigned u; } v; v.f = f;
  unsigned r = v.u + 0x7FFFu + ((v.u >> 16) & 1u);  // RNE
  return (unsigned short)(r >> 16);
}

__device__ __forceinline__ float silu_f(float v) {
  return v / (1.0f + __expf(-v));
}

// Pre-swizzle a row-major f32 W[K][N] into bf16 MFMA-B fragment order:
// out[((ks*(N/16) + nf)*64 + lane)*8 + j] = W[ks*32 + (lane>>4)*8 + j][nf*16 + (lane&15)]
__global__ void swz_kernel(const float* __restrict__ W,
                           unsigned short* __restrict__ out, int K, int N) {
  int t = blockIdx.x * 256 + threadIdx.x;
  if (t >= K * N) return;
  int j = t & 7;
  int l = (t >> 3) & 63;
  int rest = t >> 9;
  int nfr = N >> 4;
  int nf = rest % nfr;
  int ks = rest / nfr;
  int k = ks * 32 + (l >> 4) * 8 + j;
  int n = nf * 16 + (l & 15);
  out[t] = f2bf(W[k * N + n]);
}

__global__ void hist_kernel(const int* __restrict__ recv, int* __restrict__ cnt) {
  int e = blockIdx.x * 256 + threadIdx.x;
  if (e < E_EDGES) atomicAdd(&cnt[recv[e]], 1);
}

// Edge layer-1: h = silu(concat(ea, x) @ w1e + b1e); atomic scatter into s[b][recv][256]
__global__ __launch_bounds__(256) void edge_kernel(
    const float* __restrict__ x, const float* __restrict__ edge_attr,
    const int* __restrict__ recv, const float* __restrict__ w1e,
    const float* __restrict__ b1e, const unsigned short* __restrict__ w1sw,
    float* __restrict__ s) {
  __shared__ unsigned short As[64 * 136];  // 64 edges x 128 k, pad to 136 (bank stride 4)
  __shared__ float eas[256];               // 64 edges x 4 edge_attr
  __shared__ float w1lds[1024];            // w1e rows 0..3 (edge_attr part)
  __shared__ float b1lds[256];
  __shared__ int   ri[64];

  const int tid = threadIdx.x;
  const int l  = tid & 63;
  const int w  = tid >> 6;
  const int lo = l & 15, hi = l >> 4;
  const int e0 = blockIdx.x * 64;
  const int b  = blockIdx.y;

  // stage x tile (contiguous 64x128 f32) -> bf16 LDS
  const float4* xb = (const float4*)(x + ((size_t)b * E_EDGES + e0) * DX);
#pragma unroll
  for (int i = 0; i < 8; ++i) {
    int f = i * 256 + tid;                 // float4 index, 0..2047
    float4 v = xb[f];
    int g = f * 4;
    int row = g >> 7, col = g & 127;
    ushort4 p;
    p.x = f2bf(v.x); p.y = f2bf(v.y); p.z = f2bf(v.z); p.w = f2bf(v.w);
    *(ushort4*)&As[row * 136 + col] = p;
  }
  eas[tid]   = edge_attr[(size_t)e0 * 4 + tid];
  w1lds[tid]       = w1e[tid];
  w1lds[256 + tid] = w1e[256 + tid];
  w1lds[512 + tid] = w1e[512 + tid];
  w1lds[768 + tid] = w1e[768 + tid];
  b1lds[tid] = b1e[tid];
  if (tid < 64) ri[tid] = recv[e0 + tid];
  __syncthreads();

  f32x4 acc[4][4] = {};
#pragma unroll
  for (int kk = 0; kk < 4; ++kk) {
    bf16x8 a[4], bb[4];
#pragma unroll
    for (int mf = 0; mf < 4; ++mf)
      a[mf] = *(const bf16x8*)&As[(mf * 16 + lo) * 136 + kk * 32 + hi * 8];
#pragma unroll
    for (int nf = 0; nf < 4; ++nf)
      bb[nf] = *(const bf16x8*)&w1sw[(size_t)(((kk * 16) + (w * 4 + nf)) * 64 + l) * 8];
#pragma unroll
    for (int mf = 0; mf < 4; ++mf)
#pragma unroll
      for (int nf = 0; nf < 4; ++nf)
        acc[mf][nf] = __builtin_amdgcn_mfma_f32_16x16x32_bf16(a[mf], bb[nf], acc[mf][nf], 0, 0, 0);
  }

  // epilogue: + b1e + edge_attr rank-4 contribution, silu, atomic scatter
#pragma unroll
  for (int mf = 0; mf < 4; ++mf) {
#pragma unroll
    for (int nf = 0; nf < 4; ++nf) {
      const int col = w * 64 + nf * 16 + lo;
      const float w0 = w1lds[col], w1_ = w1lds[256 + col];
      const float w2_ = w1lds[512 + col], w3 = w1lds[768 + col];
      const float bb1 = b1lds[col];
#pragma unroll
      for (int j = 0; j < 4; ++j) {
        const int row = mf * 16 + hi * 4 + j;
        float v = acc[mf][nf][j] + bb1
                + eas[row * 4 + 0] * w0 + eas[row * 4 + 1] * w1_
                + eas[row * 4 + 2] * w2_ + eas[row * 4 + 3] * w3;
        v = silu_f(v);
        atomicAdd(&s[((size_t)b * NRECV + ri[row]) * 256 + col], v);
      }
    }
  }
}

__device__ __forceinline__ void gemm64(const unsigned short* Ns,
                                       const unsigned short* __restrict__ Bsw,
                                       int w, int l, f32x4 acc[4][4]) {
  const int lo = l & 15, hi = l >> 4;
#pragma unroll
  for (int kk = 0; kk < 8; ++kk) {
    bf16x8 a[4], bb[4];
#pragma unroll
    for (int mf = 0; mf < 4; ++mf)
      a[mf] = *(const bf16x8*)&Ns[(mf * 16 + lo) * 264 + kk * 32 + hi * 8];
#pragma unroll
    for (int nf = 0; nf < 4; ++nf)
      bb[nf] = *(const bf16x8*)&Bsw[(size_t)(((kk * 16) + (w * 4 + nf)) * 64 + l) * 8];
#pragma unroll
    for (int mf = 0; mf < 4; ++mf)
#pragma unroll
      for (int nf = 0; nf < 4; ++nf)
        acc[mf][nf] = __builtin_amdgcn_mfma_f32_16x16x32_bf16(a[mf], bb[nf], acc[mf][nf], 0, 0, 0);
  }
}

// Node pass: vm = s@w2e + cnt*b2e; out = silu(vm@w1f + b1f)@w2f + b2f
__global__ __launch_bounds__(256) void node_kernel(
    const float* __restrict__ s, const int* __restrict__ cnt,
    const unsigned short* __restrict__ w2esw, const float* __restrict__ b2e,
    const unsigned short* __restrict__ w1fsw, const float* __restrict__ b1f,
    const unsigned short* __restrict__ w2fsw, const float* __restrict__ b2f,
    float* __restrict__ out) {
  __shared__ unsigned short Ns[64 * 264];  // 64 rows x 256 k, pad to 264
  __shared__ int   cntl[64];
  __shared__ float bias1[256], bias2[256], bias3[256];

  const int tid = threadIdx.x;
  const int l  = tid & 63;
  const int w  = tid >> 6;
  const int lo = l & 15, hi = l >> 4;
  const int r0 = blockIdx.x * 64;
  const int b  = blockIdx.y;

  const float4* sb = (const float4*)(s + ((size_t)b * NRECV + r0) * 256);
#pragma unroll
  for (int i = 0; i < 16; ++i) {
    int f = i * 256 + tid;                 // 0..4095 float4s over 64x256
    float4 v = sb[f];
    int g = f * 4;
    int row = g >> 8, col = g & 255;
    ushort4 p;
    p.x = f2bf(v.x); p.y = f2bf(v.y); p.z = f2bf(v.z); p.w = f2bf(v.w);
    *(ushort4*)&Ns[row * 264 + col] = p;
  }
  if (tid < 64) cntl[tid] = cnt[r0 + tid];
  bias1[tid] = b2e[tid];
  bias2[tid] = b1f[tid];
  bias3[tid] = b2f[tid];
  __syncthreads();

  // GEMM1: vm = s @ w2e + cnt * b2e
  {
    f32x4 acc[4][4] = {};
    gemm64(Ns, w2esw, w, l, acc);
    __syncthreads();  // all waves done reading Ns
#pragma unroll
    for (int mf = 0; mf < 4; ++mf)
#pragma unroll
      for (int nf = 0; nf < 4; ++nf) {
        const int col = w * 64 + nf * 16 + lo;
#pragma unroll
        for (int j = 0; j < 4; ++j) {
          const int row = mf * 16 + hi * 4 + j;
          float v = acc[mf][nf][j] + (float)cntl[row] * bias1[col];
          Ns[row * 264 + col] = f2bf(v);
        }
      }
    __syncthreads();
  }

  // GEMM2: u = silu(vm @ w1f + b1f)
  {
    f32x4 acc[4][4] = {};
    gemm64(Ns, w1fsw, w, l, acc);
    __syncthreads();
#pragma unroll
    for (int mf = 0; mf < 4; ++mf)
#pragma unroll
      for (int nf = 0; nf < 4; ++nf) {
        const int col = w * 64 + nf * 16 + lo;
#pragma unroll
        for (int j = 0; j < 4; ++j) {
          const int row = mf * 16 + hi * 4 + j;
          float v = silu_f(acc[mf][nf][j] + bias2[col]);
          Ns[row * 264 + col] = f2bf(v);
        }
      }
    __syncthreads();
  }

  // GEMM3: out = u @ w2f + b2f
  {
    f32x4 acc[4][4] = {};
    gemm64(Ns, w2fsw, w, l, acc);
#pragma unroll
    for (int mf = 0; mf < 4; ++mf)
#pragma unroll
      for (int nf = 0; nf < 4; ++nf) {
        const int col = w * 64 + nf * 16 + lo;
#pragma unroll
        for (int j = 0; j < 4; ++j) {
          const int row = mf * 16 + hi * 4 + j;
          out[((size_t)b * NRECV + r0 + row) * 256 + col] = acc[mf][nf][j] + bias3[col];
        }
      }
  }
}

extern "C" void kernel_launch(void* const* d_in, const int* in_sizes, int n_in,
                              void* d_out, int out_size, void* d_ws, size_t ws_size,
                              hipStream_t stream) {
  const float* x         = (const float*)d_in[0];
  const float* edge_attr = (const float*)d_in[1];
  const int*   edge_idx  = (const int*)d_in[2];
  const float* w1e       = (const float*)d_in[3];
  const float* b1e       = (const float*)d_in[4];
  const float* w2e       = (const float*)d_in[5];
  const float* b2e       = (const float*)d_in[6];
  const float* w1f       = (const float*)d_in[7];
  const float* b1f       = (const float*)d_in[8];
  const float* w2f       = (const float*)d_in[9];
  const float* b2f       = (const float*)d_in[10];
  float* out = (float*)d_out;

  char* ws = (char*)d_ws;
  float*          sbuf  = (float*)(ws + 0);                    // 2*12288*256*4 = 25165824
  int*            cnt   = (int*)(ws + 25165824);               // 49152
  unsigned short* w1sw  = (unsigned short*)(ws + 25214976);    // 128*256*2 = 65536
  unsigned short* w2esw = (unsigned short*)(ws + 25280512);    // 256*256*2 = 131072
  unsigned short* w1fsw = (unsigned short*)(ws + 25411584);    // 131072
  unsigned short* w2fsw = (unsigned short*)(ws + 25542656);    // 131072

  hipMemsetAsync(sbuf, 0, 25165824 + 49152, stream);

  swz_kernel<<<(128 * 256) / 256, 256, 0, stream>>>(w1e + 4 * 256, w1sw, 128, 256);
  swz_kernel<<<(256 * 256) / 256, 256, 0, stream>>>(w2e, w2esw, 256, 256);
  swz_kernel<<<(256 * 256) / 256, 256, 0, stream>>>(w1f, w1fsw, 256, 256);
  swz_kernel<<<(256 * 256) / 256, 256, 0, stream>>>(w2f, w2fsw, 256, 256);

  const int* recv = edge_idx + E_EDGES;  // edge_index[1]
  hist_kernel<<<E_EDGES / 256, 256, 0, stream>>>(recv, cnt);

  dim3 eg(E_EDGES / 64, BATCH);
  edge_kernel<<<eg, 256, 0, stream>>>(x, edge_attr, recv, w1e, b1e, w1sw, sbuf);

  dim3 ng(NRECV / 64, BATCH);
  node_kernel<<<ng, 256, 0, stream>>>(sbuf, cnt, w2esw, b2e, w1fsw, b1f, w2fsw, b2f, out);
}

// Round 2
// 397.753 us; speedup vs baseline: 1.7669x; 1.7669x over previous
//
#include <hip/hip_runtime.h>
#include <hip/hip_bf16.h>

#define E_EDGES 393216
#define NRECV   12288
#define DX      128
#define BATCH   2

typedef short bf16x8 __attribute__((ext_vector_type(8)));
typedef float f32x4  __attribute__((ext_vector_type(4)));

__device__ __forceinline__ unsigned short f2bf(float f) {
  union { float f; unsigned u; } v; v.f = f;
  unsigned r = v.u + 0x7FFFu + ((v.u >> 16) & 1u);  // RNE
  return (unsigned short)(r >> 16);
}

__device__ __forceinline__ float silu_f(float v) {
  return v / (1.0f + __expf(-v));
}

// Pre-swizzle a row-major f32 W[K][N] into bf16 MFMA-B fragment order:
// out[((ks*(N/16) + nf)*64 + lane)*8 + j] = W[ks*32 + (lane>>4)*8 + j][nf*16 + (lane&15)]
__global__ void swz_kernel(const float* __restrict__ W,
                           unsigned short* __restrict__ out, int K, int N) {
  int t = blockIdx.x * 256 + threadIdx.x;
  if (t >= K * N) return;
  int j = t & 7;
  int l = (t >> 3) & 63;
  int rest = t >> 9;
  int nfr = N >> 4;
  int nf = rest % nfr;
  int ks = rest / nfr;
  int k = ks * 32 + (l >> 4) * 8 + j;
  int n = nf * 16 + (l & 15);
  out[t] = f2bf(W[k * N + n]);
}

__global__ void hist_kernel(const int* __restrict__ recv, int* __restrict__ cnt) {
  int e = blockIdx.x * 256 + threadIdx.x;
  if (e < E_EDGES) atomicAdd(&cnt[recv[e]], 1);
}

// exclusive prefix of cnt[12288] -> head[12288]; single block of 256
__global__ __launch_bounds__(256) void scan_kernel(const int* __restrict__ cnt,
                                                   int* __restrict__ head) {
  __shared__ int ts[256];
  const int t = threadIdx.x;
  const int base = t * 48;
  int s = 0;
#pragma unroll
  for (int i = 0; i < 48; ++i) s += cnt[base + i];
  ts[t] = s;
  __syncthreads();
  for (int d = 1; d < 256; d <<= 1) {
    int v = (t >= d) ? ts[t - d] : 0;
    __syncthreads();
    ts[t] += v;
    __syncthreads();
  }
  int run = (t == 0) ? 0 : ts[t - 1];
  for (int i = 0; i < 48; ++i) { head[base + i] = run; run += cnt[base + i]; }
}

__global__ void scatter_kernel(const int* __restrict__ recv, int* __restrict__ head,
                               int* __restrict__ perm) {
  int e = blockIdx.x * 256 + threadIdx.x;
  if (e < E_EDGES) {
    int pos = atomicAdd(&head[recv[e]], 1);
    perm[pos] = e;
  }
}

// Edge layer-1 over receiver-sorted edges: h = silu(concat(ea,x)@w1e + b1e),
// segmented-reduced per receiver, few atomics into s[b][recv][256].
__global__ __launch_bounds__(256) void edge_kernel(
    const float* __restrict__ x, const float* __restrict__ edge_attr,
    const int* __restrict__ recv, const int* __restrict__ perm,
    const float* __restrict__ w1e, const float* __restrict__ b1e,
    const unsigned short* __restrict__ w1sw, float* __restrict__ s) {
  __shared__ float hs[64 * 258];   // 66048 B; low 17408 B doubles as bf16 As[64][136]
  __shared__ float eas[256];       // 64 rows x 4 edge_attr
  __shared__ float w1lds[1024];    // w1e rows 0..3 (edge_attr part)
  __shared__ float b1lds[256];
  __shared__ int   ev[64];
  __shared__ int   rs[64];
  unsigned short* As = (unsigned short*)hs;

  const int tid = threadIdx.x;
  const int l  = tid & 63;
  const int w  = tid >> 6;
  const int lo = l & 15, hi = l >> 4;
  const int p0 = blockIdx.x * 64;
  const int b  = blockIdx.y;

  if (tid < 64) {
    int e = perm[p0 + tid];
    ev[tid] = e;
    rs[tid] = recv[e];
  }
  w1lds[tid]       = w1e[tid];
  w1lds[256 + tid] = w1e[256 + tid];
  w1lds[512 + tid] = w1e[512 + tid];
  w1lds[768 + tid] = w1e[768 + tid];
  b1lds[tid] = b1e[tid];
  __syncthreads();

  // gather x rows (4 threads per row, 128B contiguous each) -> bf16 LDS
  {
    const int r = tid >> 2, q = tid & 3;
    const int e = ev[r];
    const float4* xr = (const float4*)(x + ((size_t)b * E_EDGES + e) * DX);
#pragma unroll
    for (int i = 0; i < 8; ++i) {
      float4 v = xr[q * 8 + i];
      ushort4 p;
      p.x = f2bf(v.x); p.y = f2bf(v.y); p.z = f2bf(v.z); p.w = f2bf(v.w);
      *(ushort4*)&As[r * 136 + (q * 8 + i) * 4] = p;
    }
  }
  if (tid < 64) {
    float4 ea = *(const float4*)(edge_attr + (size_t)ev[tid] * 4);
    *(float4*)&eas[tid * 4] = ea;
  }
  __syncthreads();

  f32x4 acc[4][4] = {};
#pragma unroll
  for (int kk = 0; kk < 4; ++kk) {
    bf16x8 a[4], bb[4];
#pragma unroll
    for (int mf = 0; mf < 4; ++mf)
      a[mf] = *(const bf16x8*)&As[(mf * 16 + lo) * 136 + kk * 32 + hi * 8];
#pragma unroll
    for (int nf = 0; nf < 4; ++nf)
      bb[nf] = *(const bf16x8*)&w1sw[(size_t)(((kk * 16) + (w * 4 + nf)) * 64 + l) * 8];
#pragma unroll
    for (int mf = 0; mf < 4; ++mf)
#pragma unroll
      for (int nf = 0; nf < 4; ++nf)
        acc[mf][nf] = __builtin_amdgcn_mfma_f32_16x16x32_bf16(a[mf], bb[nf], acc[mf][nf], 0, 0, 0);
  }
  __syncthreads();  // As reads done; hs reuses the space

  // epilogue: bias + edge_attr rank-4 + silu -> hs[row][col] (stride 258: hi*4*258 % 32 spreads banks)
#pragma unroll
  for (int mf = 0; mf < 4; ++mf) {
#pragma unroll
    for (int nf = 0; nf < 4; ++nf) {
      const int col = w * 64 + nf * 16 + lo;
      const float w0 = w1lds[col], w1_ = w1lds[256 + col];
      const float w2_ = w1lds[512 + col], w3 = w1lds[768 + col];
      const float bb1 = b1lds[col];
#pragma unroll
      for (int j = 0; j < 4; ++j) {
        const int row = mf * 16 + hi * 4 + j;
        float v = acc[mf][nf][j] + bb1
                + eas[row * 4 + 0] * w0 + eas[row * 4 + 1] * w1_
                + eas[row * 4 + 2] * w2_ + eas[row * 4 + 3] * w3;
        hs[row * 258 + col] = silu_f(v);
      }
    }
  }
  __syncthreads();

  // segmented column-walk reduction: one atomic per (segment, column)
  {
    float run = 0.0f;
#pragma unroll 8
    for (int r = 0; r < 64; ++r) {
      run += hs[r * 258 + tid];
      if (r == 63 || rs[r + 1] != rs[r]) {
        atomicAdd(&s[((size_t)b * NRECV + rs[r]) * 256 + tid], run);
        run = 0.0f;
      }
    }
  }
}

__device__ __forceinline__ void gemm64(const unsigned short* Ns,
                                       const unsigned short* __restrict__ Bsw,
                                       int w, int l, f32x4 acc[4][4]) {
  const int lo = l & 15, hi = l >> 4;
#pragma unroll
  for (int kk = 0; kk < 8; ++kk) {
    bf16x8 a[4], bb[4];
#pragma unroll
    for (int mf = 0; mf < 4; ++mf)
      a[mf] = *(const bf16x8*)&Ns[(mf * 16 + lo) * 264 + kk * 32 + hi * 8];
#pragma unroll
    for (int nf = 0; nf < 4; ++nf)
      bb[nf] = *(const bf16x8*)&Bsw[(size_t)(((kk * 16) + (w * 4 + nf)) * 64 + l) * 8];
#pragma unroll
    for (int mf = 0; mf < 4; ++mf)
#pragma unroll
      for (int nf = 0; nf < 4; ++nf)
        acc[mf][nf] = __builtin_amdgcn_mfma_f32_16x16x32_bf16(a[mf], bb[nf], acc[mf][nf], 0, 0, 0);
  }
}

// Node pass: vm = s@w2e + cnt*b2e; out = silu(vm@w1f + b1f)@w2f + b2f
__global__ __launch_bounds__(256) void node_kernel(
    const float* __restrict__ s, const int* __restrict__ cnt,
    const unsigned short* __restrict__ w2esw, const float* __restrict__ b2e,
    const unsigned short* __restrict__ w1fsw, const float* __restrict__ b1f,
    const unsigned short* __restrict__ w2fsw, const float* __restrict__ b2f,
    float* __restrict__ out) {
  __shared__ unsigned short Ns[64 * 264];
  __shared__ int   cntl[64];
  __shared__ float bias1[256], bias2[256], bias3[256];

  const int tid = threadIdx.x;
  const int l  = tid & 63;
  const int w  = tid >> 6;
  const int lo = l & 15, hi = l >> 4;
  const int r0 = blockIdx.x * 64;
  const int b  = blockIdx.y;

  const float4* sb = (const float4*)(s + ((size_t)b * NRECV + r0) * 256);
#pragma unroll
  for (int i = 0; i < 16; ++i) {
    int f = i * 256 + tid;
    float4 v = sb[f];
    int g = f * 4;
    int row = g >> 8, col = g & 255;
    ushort4 p;
    p.x = f2bf(v.x); p.y = f2bf(v.y); p.z = f2bf(v.z); p.w = f2bf(v.w);
    *(ushort4*)&Ns[row * 264 + col] = p;
  }
  if (tid < 64) cntl[tid] = cnt[r0 + tid];
  bias1[tid] = b2e[tid];
  bias2[tid] = b1f[tid];
  bias3[tid] = b2f[tid];
  __syncthreads();

  {
    f32x4 acc[4][4] = {};
    gemm64(Ns, w2esw, w, l, acc);
    __syncthreads();
#pragma unroll
    for (int mf = 0; mf < 4; ++mf)
#pragma unroll
      for (int nf = 0; nf < 4; ++nf) {
        const int col = w * 64 + nf * 16 + lo;
#pragma unroll
        for (int j = 0; j < 4; ++j) {
          const int row = mf * 16 + hi * 4 + j;
          float v = acc[mf][nf][j] + (float)cntl[row] * bias1[col];
          Ns[row * 264 + col] = f2bf(v);
        }
      }
    __syncthreads();
  }
  {
    f32x4 acc[4][4] = {};
    gemm64(Ns, w1fsw, w, l, acc);
    __syncthreads();
#pragma unroll
    for (int mf = 0; mf < 4; ++mf)
#pragma unroll
      for (int nf = 0; nf < 4; ++nf) {
        const int col = w * 64 + nf * 16 + lo;
#pragma unroll
        for (int j = 0; j < 4; ++j) {
          const int row = mf * 16 + hi * 4 + j;
          float v = silu_f(acc[mf][nf][j] + bias2[col]);
          Ns[row * 264 + col] = f2bf(v);
        }
      }
    __syncthreads();
  }
  {
    f32x4 acc[4][4] = {};
    gemm64(Ns, w2fsw, w, l, acc);
#pragma unroll
    for (int mf = 0; mf < 4; ++mf)
#pragma unroll
      for (int nf = 0; nf < 4; ++nf) {
        const int col = w * 64 + nf * 16 + lo;
#pragma unroll
        for (int j = 0; j < 4; ++j) {
          const int row = mf * 16 + hi * 4 + j;
          out[((size_t)b * NRECV + r0 + row) * 256 + col] = acc[mf][nf][j] + bias3[col];
        }
      }
  }
}

extern "C" void kernel_launch(void* const* d_in, const int* in_sizes, int n_in,
                              void* d_out, int out_size, void* d_ws, size_t ws_size,
                              hipStream_t stream) {
  const float* x         = (const float*)d_in[0];
  const float* edge_attr = (const float*)d_in[1];
  const int*   edge_idx  = (const int*)d_in[2];
  const float* w1e       = (const float*)d_in[3];
  const float* b1e       = (const float*)d_in[4];
  const float* w2e       = (const float*)d_in[5];
  const float* b2e       = (const float*)d_in[6];
  const float* w1f       = (const float*)d_in[7];
  const float* b1f       = (const float*)d_in[8];
  const float* w2f       = (const float*)d_in[9];
  const float* b2f       = (const float*)d_in[10];
  float* out = (float*)d_out;

  char* ws = (char*)d_ws;
  float*          sbuf  = (float*)(ws + 0);                    // 25165824
  int*            cnt   = (int*)(ws + 25165824);               // 49152
  int*            head  = (int*)(ws + 25214976);               // 49152
  int*            perm  = (int*)(ws + 25264128);               // 1572864
  unsigned short* w1sw  = (unsigned short*)(ws + 26836992);    // 65536
  unsigned short* w2esw = (unsigned short*)(ws + 26902528);    // 131072
  unsigned short* w1fsw = (unsigned short*)(ws + 27033600);    // 131072
  unsigned short* w2fsw = (unsigned short*)(ws + 27164672);    // 131072

  hipMemsetAsync(sbuf, 0, 25165824 + 49152, stream);  // s + cnt

  swz_kernel<<<(128 * 256) / 256, 256, 0, stream>>>(w1e + 4 * 256, w1sw, 128, 256);
  swz_kernel<<<(256 * 256) / 256, 256, 0, stream>>>(w2e, w2esw, 256, 256);
  swz_kernel<<<(256 * 256) / 256, 256, 0, stream>>>(w1f, w1fsw, 256, 256);
  swz_kernel<<<(256 * 256) / 256, 256, 0, stream>>>(w2f, w2fsw, 256, 256);

  const int* recv = edge_idx + E_EDGES;  // edge_index[1]
  hist_kernel<<<E_EDGES / 256, 256, 0, stream>>>(recv, cnt);
  scan_kernel<<<1, 256, 0, stream>>>(cnt, head);
  scatter_kernel<<<E_EDGES / 256, 256, 0, stream>>>(recv, head, perm);

  dim3 eg(E_EDGES / 64, BATCH);
  edge_kernel<<<eg, 256, 0, stream>>>(x, edge_attr, recv, perm, w1e, b1e, w1sw, sbuf);

  dim3 ng(NRECV / 64, BATCH);
  node_kernel<<<ng, 256, 0, stream>>>(sbuf, cnt, w2esw, b2e, w1fsw, b1f, w2fsw, b2f, out);
}

// Round 3
// 296.496 us; speedup vs baseline: 2.3703x; 1.3415x over previous
//
#include <hip/hip_runtime.h>
#include <hip/hip_bf16.h>

#define E_EDGES 393216
#define NRECV   12288
#define DX      128
#define BATCH   2

typedef short bf16x8 __attribute__((ext_vector_type(8)));
typedef float f32x4  __attribute__((ext_vector_type(4)));

__device__ __forceinline__ unsigned short f2bf(float f) {
  union { float f; unsigned u; } v; v.f = f;
  unsigned r = v.u + 0x7FFFu + ((v.u >> 16) & 1u);  // RNE
  return (unsigned short)(r >> 16);
}

__device__ __forceinline__ unsigned pk2(float a, float b) {
  __hip_bfloat162 h = __float22bfloat162_rn(make_float2(a, b));
  union { __hip_bfloat162 h; unsigned u; } c; c.h = h;
  return c.u;
}

__device__ __forceinline__ float silu_f(float v) {
  return v / (1.0f + __expf(-v));
}

// Pre-swizzle a row-major f32 W[K][N] into bf16 MFMA-B fragment order.
__global__ void swz_kernel(const float* __restrict__ W,
                           unsigned short* __restrict__ out, int K, int N) {
  int t = blockIdx.x * 256 + threadIdx.x;
  if (t >= K * N) return;
  int j = t & 7;
  int l = (t >> 3) & 63;
  int rest = t >> 9;
  int nfr = N >> 4;
  int nf = rest % nfr;
  int ks = rest / nfr;
  int k = ks * 32 + (l >> 4) * 8 + j;
  int n = nf * 16 + (l & 15);
  out[t] = f2bf(W[k * N + n]);
}

// w1e with K padded 132 -> 160 (rows >=132 are zero), N=256
__global__ void swz_w1e_kernel(const float* __restrict__ W,
                               unsigned short* __restrict__ out) {
  int t = blockIdx.x * 256 + threadIdx.x;  // 160*256 = 40960
  int j = t & 7;
  int l = (t >> 3) & 63;
  int rest = t >> 9;
  int nf = rest & 15;
  int ks = rest >> 4;
  int k = ks * 32 + (l >> 4) * 8 + j;
  int n = nf * 16 + (l & 15);
  out[t] = (k < 132) ? f2bf(W[k * 256 + n]) : (unsigned short)0;
}

__global__ void hist_kernel(const int* __restrict__ recv, int* __restrict__ cnt) {
  int e = blockIdx.x * 256 + threadIdx.x;
  if (e < E_EDGES) atomicAdd(&cnt[recv[e]], 1);
}

// exclusive prefix of cnt[12288] -> head[12288]; single block of 256
__global__ __launch_bounds__(256) void scan_kernel(const int* __restrict__ cnt,
                                                   int* __restrict__ head) {
  __shared__ int ts[256];
  const int t = threadIdx.x;
  const int base = t * 48;
  int s = 0;
#pragma unroll
  for (int i = 0; i < 48; ++i) s += cnt[base + i];
  ts[t] = s;
  __syncthreads();
  for (int d = 1; d < 256; d <<= 1) {
    int v = (t >= d) ? ts[t - d] : 0;
    __syncthreads();
    ts[t] += v;
    __syncthreads();
  }
  int run = (t == 0) ? 0 : ts[t - 1];
  for (int i = 0; i < 48; ++i) { head[base + i] = run; run += cnt[base + i]; }
}

__global__ void scatter_kernel(const int* __restrict__ recv, int* __restrict__ head,
                               int* __restrict__ perm) {
  int e = blockIdx.x * 256 + threadIdx.x;
  if (e < E_EDGES) {
    int pos = atomicAdd(&head[recv[e]], 1);
    perm[pos] = e;
  }
}

// Edge layer-1 over receiver-sorted edges. K padded to 160: cols 0..3 = edge_attr,
// cols 4..131 = x, cols 132..159 = 0 (matching zero rows in w1sw).
// As is XOR-swizzled (byte ^= (row&7)<<4 within 128B windows) -> conflict-free b128 reads.
__global__ __launch_bounds__(256, 4) void edge_kernel(
    const float* __restrict__ x, const float* __restrict__ edge_attr,
    const int* __restrict__ recv, const int* __restrict__ perm,
    const float* __restrict__ b1e, const unsigned short* __restrict__ w1sw,
    float* __restrict__ s) {
  __shared__ unsigned short hs[64 * 264];  // 33792 B; first 24576 B aliased as As[64][384B]
  __shared__ float b1lds[256];
  __shared__ int ev[64];
  __shared__ int rs[64];
  char* As = (char*)hs;

  const int tid = threadIdx.x;
  const int l  = tid & 63;
  const int w  = tid >> 6;
  const int lo = l & 15, hi = l >> 4;
  const int p0 = blockIdx.x * 64;
  const int b  = blockIdx.y;

  if (tid < 64) {
    int e = perm[p0 + tid];
    ev[tid] = e;
    rs[tid] = recv[e];
  }
  b1lds[tid] = b1e[tid];
  // zero pad cols 132..159 (+ slack): bytes 264..383 of each row, swizzled
  for (int idx = tid; idx < 960; idx += 256) {
    int r = idx / 15, k2 = idx - r * 15;
    int byte0 = 264 + 8 * k2;
    *(uint2*)(As + r * 384 + (byte0 ^ ((r & 7) << 4))) = make_uint2(0u, 0u);
  }
  __syncthreads();

  // gather x rows (4 threads/row, 128B contiguous each) + edge_attr -> swizzled bf16 As
  {
    const int r = tid >> 2, q = tid & 3;
    const int e = ev[r];
    const int rx = (r & 7) << 4;
    const float4* xr = (const float4*)(x + ((size_t)b * E_EDGES + e) * DX);
#pragma unroll
    for (int i = 0; i < 8; ++i) {
      int t = q * 8 + i;
      float4 v = xr[t];
      int byte0 = 8 + 8 * t;
      *(uint2*)(As + r * 384 + (byte0 ^ rx)) = make_uint2(pk2(v.x, v.y), pk2(v.z, v.w));
    }
    if (tid < 64) {
      float4 ea = *(const float4*)(edge_attr + (size_t)ev[tid] * 4);
      *(uint2*)(As + tid * 384 + ((tid & 7) << 4)) =
          make_uint2(pk2(ea.x, ea.y), pk2(ea.z, ea.w));
    }
  }
  __syncthreads();

  f32x4 acc[4][4] = {};
  const int axor = (lo & 7) << 4;  // row&7 == lo&7 since rows are mf*16+lo
#pragma unroll
  for (int kk = 0; kk < 5; ++kk) {
    bf16x8 a[4], bb[4];
#pragma unroll
    for (int mf = 0; mf < 4; ++mf)
      a[mf] = *(const bf16x8*)(As + (mf * 16 + lo) * 384 + ((kk * 64 + hi * 16) ^ axor));
#pragma unroll
    for (int nf = 0; nf < 4; ++nf)
      bb[nf] = *(const bf16x8*)&w1sw[(size_t)(((kk * 16) + (w * 4 + nf)) * 64 + l) * 8];
#pragma unroll
    for (int mf = 0; mf < 4; ++mf)
#pragma unroll
      for (int nf = 0; nf < 4; ++nf)
        acc[mf][nf] = __builtin_amdgcn_mfma_f32_16x16x32_bf16(a[mf], bb[nf], acc[mf][nf], 0, 0, 0);
  }
  __syncthreads();  // As reads done; hs reuses the space

  // epilogue: + b1e, silu -> bf16 hs
#pragma unroll
  for (int mf = 0; mf < 4; ++mf) {
#pragma unroll
    for (int nf = 0; nf < 4; ++nf) {
      const int col = w * 64 + nf * 16 + lo;
      const float bb1 = b1lds[col];
#pragma unroll
      for (int j = 0; j < 4; ++j) {
        const int row = mf * 16 + hi * 4 + j;
        hs[row * 264 + col] = f2bf(silu_f(acc[mf][nf][j] + bb1));
      }
    }
  }
  __syncthreads();

  // segmented column-walk reduction; boundary mask is wave-uniform (scalar branch)
  {
    int flag = (l == 63) || (rs[l + 1] != rs[l]);
    unsigned long long segmask = __ballot(flag);
    float* sb = s + (size_t)b * NRECV * 256 + tid;
    float run = 0.0f;
#pragma unroll
    for (int r = 0; r < 64; ++r) {
      union { unsigned u; float f; } c;
      c.u = (unsigned)hs[r * 264 + tid] << 16;
      run += c.f;
      if ((segmask >> r) & 1ull) {
        atomicAdd(sb + (size_t)rs[r] * 256, run);
        run = 0.0f;
      }
    }
  }
}

__device__ __forceinline__ void gemm64(const unsigned short* Ns,
                                       const unsigned short* __restrict__ Bsw,
                                       int w, int l, f32x4 acc[4][4]) {
  const int lo = l & 15, hi = l >> 4;
#pragma unroll
  for (int kk = 0; kk < 8; ++kk) {
    bf16x8 a[4], bb[4];
#pragma unroll
    for (int mf = 0; mf < 4; ++mf)
      a[mf] = *(const bf16x8*)&Ns[(mf * 16 + lo) * 264 + kk * 32 + hi * 8];
#pragma unroll
    for (int nf = 0; nf < 4; ++nf)
      bb[nf] = *(const bf16x8*)&Bsw[(size_t)(((kk * 16) + (w * 4 + nf)) * 64 + l) * 8];
#pragma unroll
    for (int mf = 0; mf < 4; ++mf)
#pragma unroll
      for (int nf = 0; nf < 4; ++nf)
        acc[mf][nf] = __builtin_amdgcn_mfma_f32_16x16x32_bf16(a[mf], bb[nf], acc[mf][nf], 0, 0, 0);
  }
}

// Node pass: vm = s@w2e + cnt*b2e; out = silu(vm@w1f + b1f)@w2f + b2f
__global__ __launch_bounds__(256) void node_kernel(
    const float* __restrict__ s, const int* __restrict__ cnt,
    const unsigned short* __restrict__ w2esw, const float* __restrict__ b2e,
    const unsigned short* __restrict__ w1fsw, const float* __restrict__ b1f,
    const unsigned short* __restrict__ w2fsw, const float* __restrict__ b2f,
    float* __restrict__ out) {
  __shared__ unsigned short Ns[64 * 264];
  __shared__ int   cntl[64];
  __shared__ float bias1[256], bias2[256], bias3[256];

  const int tid = threadIdx.x;
  const int l  = tid & 63;
  const int w  = tid >> 6;
  const int lo = l & 15, hi = l >> 4;
  const int r0 = blockIdx.x * 64;
  const int b  = blockIdx.y;

  const float4* sb = (const float4*)(s + ((size_t)b * NRECV + r0) * 256);
#pragma unroll
  for (int i = 0; i < 16; ++i) {
    int f = i * 256 + tid;
    float4 v = sb[f];
    int g = f * 4;
    int row = g >> 8, col = g & 255;
    *(uint2*)&Ns[row * 264 + col] = make_uint2(pk2(v.x, v.y), pk2(v.z, v.w));
  }
  if (tid < 64) cntl[tid] = cnt[r0 + tid];
  bias1[tid] = b2e[tid];
  bias2[tid] = b1f[tid];
  bias3[tid] = b2f[tid];
  __syncthreads();

  {
    f32x4 acc[4][4] = {};
    gemm64(Ns, w2esw, w, l, acc);
    __syncthreads();
#pragma unroll
    for (int mf = 0; mf < 4; ++mf)
#pragma unroll
      for (int nf = 0; nf < 4; ++nf) {
        const int col = w * 64 + nf * 16 + lo;
#pragma unroll
        for (int j = 0; j < 4; ++j) {
          const int row = mf * 16 + hi * 4 + j;
          float v = acc[mf][nf][j] + (float)cntl[row] * bias1[col];
          Ns[row * 264 + col] = f2bf(v);
        }
      }
    __syncthreads();
  }
  {
    f32x4 acc[4][4] = {};
    gemm64(Ns, w1fsw, w, l, acc);
    __syncthreads();
#pragma unroll
    for (int mf = 0; mf < 4; ++mf)
#pragma unroll
      for (int nf = 0; nf < 4; ++nf) {
        const int col = w * 64 + nf * 16 + lo;
#pragma unroll
        for (int j = 0; j < 4; ++j) {
          const int row = mf * 16 + hi * 4 + j;
          float v = silu_f(acc[mf][nf][j] + bias2[col]);
          Ns[row * 264 + col] = f2bf(v);
        }
      }
    __syncthreads();
  }
  {
    f32x4 acc[4][4] = {};
    gemm64(Ns, w2fsw, w, l, acc);
#pragma unroll
    for (int mf = 0; mf < 4; ++mf)
#pragma unroll
      for (int nf = 0; nf < 4; ++nf) {
        const int col = w * 64 + nf * 16 + lo;
#pragma unroll
        for (int j = 0; j < 4; ++j) {
          const int row = mf * 16 + hi * 4 + j;
          out[((size_t)b * NRECV + r0 + row) * 256 + col] = acc[mf][nf][j] + bias3[col];
        }
      }
  }
}

extern "C" void kernel_launch(void* const* d_in, const int* in_sizes, int n_in,
                              void* d_out, int out_size, void* d_ws, size_t ws_size,
                              hipStream_t stream) {
  const float* x         = (const float*)d_in[0];
  const float* edge_attr = (const float*)d_in[1];
  const int*   edge_idx  = (const int*)d_in[2];
  const float* w1e       = (const float*)d_in[3];
  const float* b1e       = (const float*)d_in[4];
  const float* w2e       = (const float*)d_in[5];
  const float* b2e       = (const float*)d_in[6];
  const float* w1f       = (const float*)d_in[7];
  const float* b1f       = (const float*)d_in[8];
  const float* w2f       = (const float*)d_in[9];
  const float* b2f       = (const float*)d_in[10];
  float* out = (float*)d_out;

  char* ws = (char*)d_ws;
  float*          sbuf  = (float*)(ws + 0);                    // 25165824
  int*            cnt   = (int*)(ws + 25165824);               // 49152
  int*            head  = (int*)(ws + 25214976);               // 49152
  int*            perm  = (int*)(ws + 25264128);               // 1572864
  unsigned short* w1sw  = (unsigned short*)(ws + 26836992);    // 160*256*2 = 81920
  unsigned short* w2esw = (unsigned short*)(ws + 26918912);    // 131072
  unsigned short* w1fsw = (unsigned short*)(ws + 27049984);    // 131072
  unsigned short* w2fsw = (unsigned short*)(ws + 27181056);    // 131072

  hipMemsetAsync(sbuf, 0, 25165824 + 49152, stream);  // s + cnt

  swz_w1e_kernel<<<160, 256, 0, stream>>>(w1e, w1sw);
  swz_kernel<<<(256 * 256) / 256, 256, 0, stream>>>(w2e, w2esw, 256, 256);
  swz_kernel<<<(256 * 256) / 256, 256, 0, stream>>>(w1f, w1fsw, 256, 256);
  swz_kernel<<<(256 * 256) / 256, 256, 0, stream>>>(w2f, w2fsw, 256, 256);

  const int* recv = edge_idx + E_EDGES;  // edge_index[1]
  hist_kernel<<<E_EDGES / 256, 256, 0, stream>>>(recv, cnt);
  scan_kernel<<<1, 256, 0, stream>>>(cnt, head);
  scatter_kernel<<<E_EDGES / 256, 256, 0, stream>>>(recv, head, perm);

  dim3 eg(E_EDGES / 64, BATCH);
  edge_kernel<<<eg, 256, 0, stream>>>(x, edge_attr, recv, perm, b1e, w1sw, sbuf);

  dim3 ng(NRECV / 64, BATCH);
  node_kernel<<<ng, 256, 0, stream>>>(sbuf, cnt, w2esw, b2e, w1fsw, b1f, w2fsw, b2f, out);
}

// Round 4
// 293.636 us; speedup vs baseline: 2.3934x; 1.0097x over previous
//
#include <hip/hip_runtime.h>
#include <hip/hip_bf16.h>

#define E_EDGES 393216
#define NRECV   12288
#define DX      128
#define BATCH   2

typedef short bf16x8 __attribute__((ext_vector_type(8)));
typedef float f32x4  __attribute__((ext_vector_type(4)));

__device__ __forceinline__ unsigned short f2bf(float f) {
  union { float f; unsigned u; } v; v.f = f;
  unsigned r = v.u + 0x7FFFu + ((v.u >> 16) & 1u);  // RNE
  return (unsigned short)(r >> 16);
}

__device__ __forceinline__ unsigned pk2(float a, float b) {
  __hip_bfloat162 h = __float22bfloat162_rn(make_float2(a, b));
  union { __hip_bfloat162 h; unsigned u; } c; c.h = h;
  return c.u;
}

__device__ __forceinline__ float silu_f(float v) {
  return v / (1.0f + __expf(-v));
}

// fast zero fill: n float4s, grid-stride
__global__ __launch_bounds__(256) void zero_kernel(float4* __restrict__ p, int n4) {
  int i = blockIdx.x * 256 + threadIdx.x;
  int stride = gridDim.x * 256;
  float4 z = make_float4(0.f, 0.f, 0.f, 0.f);
  for (; i < n4; i += stride) p[i] = z;
}

// Pre-swizzle a row-major f32 W[K][N] into bf16 MFMA-B fragment order.
__global__ void swz_kernel(const float* __restrict__ W,
                           unsigned short* __restrict__ out, int K, int N) {
  int t = blockIdx.x * 256 + threadIdx.x;
  if (t >= K * N) return;
  int j = t & 7;
  int l = (t >> 3) & 63;
  int rest = t >> 9;
  int nfr = N >> 4;
  int nf = rest % nfr;
  int ks = rest / nfr;
  int k = ks * 32 + (l >> 4) * 8 + j;
  int n = nf * 16 + (l & 15);
  out[t] = f2bf(W[k * N + n]);
}

// w1e with K padded 132 -> 160 (rows >=132 are zero), N=256
__global__ void swz_w1e_kernel(const float* __restrict__ W,
                               unsigned short* __restrict__ out) {
  int t = blockIdx.x * 256 + threadIdx.x;  // 160*256 = 40960
  int j = t & 7;
  int l = (t >> 3) & 63;
  int rest = t >> 9;
  int nf = rest & 15;
  int ks = rest >> 4;
  int k = ks * 32 + (l >> 4) * 8 + j;
  int n = nf * 16 + (l & 15);
  out[t] = (k < 132) ? f2bf(W[k * 256 + n]) : (unsigned short)0;
}

__global__ void hist_kernel(const int* __restrict__ recv, int* __restrict__ cnt) {
  int e = blockIdx.x * 256 + threadIdx.x;
  if (e < E_EDGES) atomicAdd(&cnt[recv[e]], 1);
}

// exclusive prefix of cnt[12288] -> head[12288]; single block of 256
__global__ __launch_bounds__(256) void scan_kernel(const int* __restrict__ cnt,
                                                   int* __restrict__ head) {
  __shared__ int ts[256];
  const int t = threadIdx.x;
  const int base = t * 48;
  int s = 0;
#pragma unroll
  for (int i = 0; i < 48; ++i) s += cnt[base + i];
  ts[t] = s;
  __syncthreads();
  for (int d = 1; d < 256; d <<= 1) {
    int v = (t >= d) ? ts[t - d] : 0;
    __syncthreads();
    ts[t] += v;
    __syncthreads();
  }
  int run = (t == 0) ? 0 : ts[t - 1];
  for (int i = 0; i < 48; ++i) { head[base + i] = run; run += cnt[base + i]; }
}

__global__ void scatter_kernel(const int* __restrict__ recv, int* __restrict__ head,
                               int* __restrict__ perm) {
  int e = blockIdx.x * 256 + threadIdx.x;
  if (e < E_EDGES) {
    int pos = atomicAdd(&head[recv[e]], 1);
    perm[pos] = e;
  }
}

// Edge layer-1 over receiver-sorted edges. K padded to 160: cols 0..3 = edge_attr,
// cols 4..131 = x, cols 132..159 = 0 (matching zero rows in w1sw).
// As is XOR-swizzled (byte ^= (row&7)<<4 within 128B windows) -> conflict-free b128 reads.
__global__ __launch_bounds__(256, 4) void edge_kernel(
    const float* __restrict__ x, const float* __restrict__ edge_attr,
    const int* __restrict__ recv, const int* __restrict__ perm,
    const float* __restrict__ b1e, const unsigned short* __restrict__ w1sw,
    float* __restrict__ s) {
  __shared__ unsigned short hs[64 * 264];  // 33792 B; first 24576 B aliased as As[64][384B]
  __shared__ float b1lds[256];
  __shared__ int ev[64];
  __shared__ int rs[64];
  char* As = (char*)hs;

  const int tid = threadIdx.x;
  const int l  = tid & 63;
  const int w  = tid >> 6;
  const int lo = l & 15, hi = l >> 4;
  const int p0 = blockIdx.x * 64;
  const int b  = blockIdx.y;

  if (tid < 64) {
    int e = perm[p0 + tid];
    ev[tid] = e;
    rs[tid] = recv[e];
  }
  b1lds[tid] = b1e[tid];
  // zero pad cols 132..159 (+ slack): bytes 264..383 of each row, swizzled
  for (int idx = tid; idx < 960; idx += 256) {
    int r = idx / 15, k2 = idx - r * 15;
    int byte0 = 264 + 8 * k2;
    *(uint2*)(As + r * 384 + (byte0 ^ ((r & 7) << 4))) = make_uint2(0u, 0u);
  }
  __syncthreads();

  // gather x rows (4 threads/row, 128B contiguous each) + edge_attr -> swizzled bf16 As
  {
    const int r = tid >> 2, q = tid & 3;
    const int e = ev[r];
    const int rx = (r & 7) << 4;
    const float4* xr = (const float4*)(x + ((size_t)b * E_EDGES + e) * DX);
#pragma unroll
    for (int i = 0; i < 8; ++i) {
      int t = q * 8 + i;
      float4 v = xr[t];
      int byte0 = 8 + 8 * t;
      *(uint2*)(As + r * 384 + (byte0 ^ rx)) = make_uint2(pk2(v.x, v.y), pk2(v.z, v.w));
    }
    if (tid < 64) {
      float4 ea = *(const float4*)(edge_attr + (size_t)ev[tid] * 4);
      *(uint2*)(As + tid * 384 + ((tid & 7) << 4)) =
          make_uint2(pk2(ea.x, ea.y), pk2(ea.z, ea.w));
    }
  }
  __syncthreads();

  f32x4 acc[4][4] = {};
  const int axor = (lo & 7) << 4;  // row&7 == lo&7 since rows are mf*16+lo
#pragma unroll
  for (int kk = 0; kk < 5; ++kk) {
    bf16x8 a[4], bb[4];
#pragma unroll
    for (int mf = 0; mf < 4; ++mf)
      a[mf] = *(const bf16x8*)(As + (mf * 16 + lo) * 384 + ((kk * 64 + hi * 16) ^ axor));
#pragma unroll
    for (int nf = 0; nf < 4; ++nf)
      bb[nf] = *(const bf16x8*)&w1sw[(size_t)(((kk * 16) + (w * 4 + nf)) * 64 + l) * 8];
#pragma unroll
    for (int mf = 0; mf < 4; ++mf)
#pragma unroll
      for (int nf = 0; nf < 4; ++nf)
        acc[mf][nf] = __builtin_amdgcn_mfma_f32_16x16x32_bf16(a[mf], bb[nf], acc[mf][nf], 0, 0, 0);
  }
  __syncthreads();  // As reads done; hs reuses the space

  // epilogue: + b1e, silu -> bf16 hs
#pragma unroll
  for (int mf = 0; mf < 4; ++mf) {
#pragma unroll
    for (int nf = 0; nf < 4; ++nf) {
      const int col = w * 64 + nf * 16 + lo;
      const float bb1 = b1lds[col];
#pragma unroll
      for (int j = 0; j < 4; ++j) {
        const int row = mf * 16 + hi * 4 + j;
        hs[row * 264 + col] = f2bf(silu_f(acc[mf][nf][j] + bb1));
      }
    }
  }
  __syncthreads();

  // segmented column-walk reduction; boundary mask is wave-uniform (scalar branch)
  {
    int flag = (l == 63) || (rs[l + 1] != rs[l]);
    unsigned long long segmask = __ballot(flag);
    float* sb = s + (size_t)b * NRECV * 256 + tid;
    float run = 0.0f;
#pragma unroll
    for (int r = 0; r < 64; ++r) {
      union { unsigned u; float f; } c;
      c.u = (unsigned)hs[r * 264 + tid] << 16;
      run += c.f;
      if ((segmask >> r) & 1ull) {
        atomicAdd(sb + (size_t)rs[r] * 256, run);
        run = 0.0f;
      }
    }
  }
}

__device__ __forceinline__ void gemm64(const unsigned short* Ns,
                                       const unsigned short* __restrict__ Bsw,
                                       int w, int l, f32x4 acc[4][4]) {
  const int lo = l & 15, hi = l >> 4;
#pragma unroll
  for (int kk = 0; kk < 8; ++kk) {
    bf16x8 a[4], bb[4];
#pragma unroll
    for (int mf = 0; mf < 4; ++mf)
      a[mf] = *(const bf16x8*)&Ns[(mf * 16 + lo) * 264 + kk * 32 + hi * 8];
#pragma unroll
    for (int nf = 0; nf < 4; ++nf)
      bb[nf] = *(const bf16x8*)&Bsw[(size_t)(((kk * 16) + (w * 4 + nf)) * 64 + l) * 8];
#pragma unroll
    for (int mf = 0; mf < 4; ++mf)
#pragma unroll
      for (int nf = 0; nf < 4; ++nf)
        acc[mf][nf] = __builtin_amdgcn_mfma_f32_16x16x32_bf16(a[mf], bb[nf], acc[mf][nf], 0, 0, 0);
  }
}

// Node pass: vm = s@w2e + cnt*b2e; out = silu(vm@w1f + b1f)@w2f + b2f
__global__ __launch_bounds__(256) void node_kernel(
    const float* __restrict__ s, const int* __restrict__ cnt,
    const unsigned short* __restrict__ w2esw, const float* __restrict__ b2e,
    const unsigned short* __restrict__ w1fsw, const float* __restrict__ b1f,
    const unsigned short* __restrict__ w2fsw, const float* __restrict__ b2f,
    float* __restrict__ out) {
  __shared__ unsigned short Ns[64 * 264];
  __shared__ int   cntl[64];
  __shared__ float bias1[256], bias2[256], bias3[256];

  const int tid = threadIdx.x;
  const int l  = tid & 63;
  const int w  = tid >> 6;
  const int lo = l & 15, hi = l >> 4;
  const int r0 = blockIdx.x * 64;
  const int b  = blockIdx.y;

  const float4* sb = (const float4*)(s + ((size_t)b * NRECV + r0) * 256);
#pragma unroll
  for (int i = 0; i < 16; ++i) {
    int f = i * 256 + tid;
    float4 v = sb[f];
    int g = f * 4;
    int row = g >> 8, col = g & 255;
    *(uint2*)&Ns[row * 264 + col] = make_uint2(pk2(v.x, v.y), pk2(v.z, v.w));
  }
  if (tid < 64) cntl[tid] = cnt[r0 + tid];
  bias1[tid] = b2e[tid];
  bias2[tid] = b1f[tid];
  bias3[tid] = b2f[tid];
  __syncthreads();

  {
    f32x4 acc[4][4] = {};
    gemm64(Ns, w2esw, w, l, acc);
    __syncthreads();
#pragma unroll
    for (int mf = 0; mf < 4; ++mf)
#pragma unroll
      for (int nf = 0; nf < 4; ++nf) {
        const int col = w * 64 + nf * 16 + lo;
#pragma unroll
        for (int j = 0; j < 4; ++j) {
          const int row = mf * 16 + hi * 4 + j;
          float v = acc[mf][nf][j] + (float)cntl[row] * bias1[col];
          Ns[row * 264 + col] = f2bf(v);
        }
      }
    __syncthreads();
  }
  {
    f32x4 acc[4][4] = {};
    gemm64(Ns, w1fsw, w, l, acc);
    __syncthreads();
#pragma unroll
    for (int mf = 0; mf < 4; ++mf)
#pragma unroll
      for (int nf = 0; nf < 4; ++nf) {
        const int col = w * 64 + nf * 16 + lo;
#pragma unroll
        for (int j = 0; j < 4; ++j) {
          const int row = mf * 16 + hi * 4 + j;
          float v = silu_f(acc[mf][nf][j] + bias2[col]);
          Ns[row * 264 + col] = f2bf(v);
        }
      }
    __syncthreads();
  }
  {
    f32x4 acc[4][4] = {};
    gemm64(Ns, w2fsw, w, l, acc);
#pragma unroll
    for (int mf = 0; mf < 4; ++mf)
#pragma unroll
      for (int nf = 0; nf < 4; ++nf) {
        const int col = w * 64 + nf * 16 + lo;
#pragma unroll
        for (int j = 0; j < 4; ++j) {
          const int row = mf * 16 + hi * 4 + j;
          out[((size_t)b * NRECV + r0 + row) * 256 + col] = acc[mf][nf][j] + bias3[col];
        }
      }
  }
}

extern "C" void kernel_launch(void* const* d_in, const int* in_sizes, int n_in,
                              void* d_out, int out_size, void* d_ws, size_t ws_size,
                              hipStream_t stream) {
  const float* x         = (const float*)d_in[0];
  const float* edge_attr = (const float*)d_in[1];
  const int*   edge_idx  = (const int*)d_in[2];
  const float* w1e       = (const float*)d_in[3];
  const float* b1e       = (const float*)d_in[4];
  const float* w2e       = (const float*)d_in[5];
  const float* b2e       = (const float*)d_in[6];
  const float* w1f       = (const float*)d_in[7];
  const float* b1f       = (const float*)d_in[8];
  const float* w2f       = (const float*)d_in[9];
  const float* b2f       = (const float*)d_in[10];
  float* out = (float*)d_out;

  char* ws = (char*)d_ws;
  float*          sbuf  = (float*)(ws + 0);                    // 25165824
  int*            cnt   = (int*)(ws + 25165824);               // 49152
  int*            head  = (int*)(ws + 25214976);               // 49152
  int*            perm  = (int*)(ws + 25264128);               // 1572864
  unsigned short* w1sw  = (unsigned short*)(ws + 26836992);    // 160*256*2 = 81920
  unsigned short* w2esw = (unsigned short*)(ws + 26918912);    // 131072
  unsigned short* w1fsw = (unsigned short*)(ws + 27049984);    // 131072
  unsigned short* w2fsw = (unsigned short*)(ws + 27181056);    // 131072

  // zero s + cnt (25214976 B = 1575936 float4s) with our own fill:
  // rocclr fillBufferAligned ran at 105 GB/s (240 us) per round-3 profile.
  zero_kernel<<<2048, 256, 0, stream>>>((float4*)ws, 1575936);

  swz_w1e_kernel<<<160, 256, 0, stream>>>(w1e, w1sw);
  swz_kernel<<<(256 * 256) / 256, 256, 0, stream>>>(w2e, w2esw, 256, 256);
  swz_kernel<<<(256 * 256) / 256, 256, 0, stream>>>(w1f, w1fsw, 256, 256);
  swz_kernel<<<(256 * 256) / 256, 256, 0, stream>>>(w2f, w2fsw, 256, 256);

  const int* recv = edge_idx + E_EDGES;  // edge_index[1]
  hist_kernel<<<E_EDGES / 256, 256, 0, stream>>>(recv, cnt);
  scan_kernel<<<1, 256, 0, stream>>>(cnt, head);
  scatter_kernel<<<E_EDGES / 256, 256, 0, stream>>>(recv, head, perm);

  dim3 eg(E_EDGES / 64, BATCH);
  edge_kernel<<<eg, 256, 0, stream>>>(x, edge_attr, recv, perm, b1e, w1sw, sbuf);

  dim3 ng(NRECV / 64, BATCH);
  node_kernel<<<ng, 256, 0, stream>>>(sbuf, cnt, w2esw, b2e, w1fsw, b1f, w2fsw, b2f, out);
}

// Round 5
// 278.637 us; speedup vs baseline: 2.5222x; 1.0538x over previous
//
#include <hip/hip_runtime.h>
#include <hip/hip_bf16.h>

#define E_EDGES 393216
#define NRECV   12288
#define DX      128
#define BATCH   2

typedef short bf16x8 __attribute__((ext_vector_type(8)));
typedef float f32x4  __attribute__((ext_vector_type(4)));

__device__ __forceinline__ unsigned short f2bf(float f) {
  union { float f; unsigned u; } v; v.f = f;
  unsigned r = v.u + 0x7FFFu + ((v.u >> 16) & 1u);  // RNE
  return (unsigned short)(r >> 16);
}

__device__ __forceinline__ unsigned pk2(float a, float b) {
  __hip_bfloat162 h = __float22bfloat162_rn(make_float2(a, b));
  union { __hip_bfloat162 h; unsigned u; } c; c.h = h;
  return c.u;
}

__device__ __forceinline__ float silu_f(float v) {
  return v / (1.0f + __expf(-v));
}

// fast zero fill: n float4s, grid-stride
__global__ __launch_bounds__(256) void zero_kernel(float4* __restrict__ p, int n4) {
  int i = blockIdx.x * 256 + threadIdx.x;
  int stride = gridDim.x * 256;
  float4 z = make_float4(0.f, 0.f, 0.f, 0.f);
  for (; i < n4; i += stride) p[i] = z;
}

// Pre-swizzle a row-major f32 W[K][N] into bf16 MFMA-B fragment order.
__global__ void swz_kernel(const float* __restrict__ W,
                           unsigned short* __restrict__ out, int K, int N) {
  int t = blockIdx.x * 256 + threadIdx.x;
  if (t >= K * N) return;
  int j = t & 7;
  int l = (t >> 3) & 63;
  int rest = t >> 9;
  int nfr = N >> 4;
  int nf = rest % nfr;
  int ks = rest / nfr;
  int k = ks * 32 + (l >> 4) * 8 + j;
  int n = nf * 16 + (l & 15);
  out[t] = f2bf(W[k * N + n]);
}

// w1e padded K 132 -> 160: rows 0..131 = w1e, row 132 = b1e (bias via 1.0 input), rest 0
__global__ void swz_w1e_kernel(const float* __restrict__ W, const float* __restrict__ bias,
                               unsigned short* __restrict__ out) {
  int t = blockIdx.x * 256 + threadIdx.x;  // 160*256 = 40960
  int j = t & 7;
  int l = (t >> 3) & 63;
  int rest = t >> 9;
  int nf = rest & 15;
  int ks = rest >> 4;
  int k = ks * 32 + (l >> 4) * 8 + j;
  int n = nf * 16 + (l & 15);
  float v = (k < 132) ? W[k * 256 + n] : (k == 132 ? bias[n] : 0.0f);
  out[t] = f2bf(v);
}

__global__ void hist_kernel(const int* __restrict__ recv, int* __restrict__ cnt) {
  int e = blockIdx.x * 256 + threadIdx.x;
  if (e < E_EDGES) atomicAdd(&cnt[recv[e]], 1);
}

// exclusive prefix of cnt[12288] -> head[12288]; single block of 256
__global__ __launch_bounds__(256) void scan_kernel(const int* __restrict__ cnt,
                                                   int* __restrict__ head) {
  __shared__ int ts[256];
  const int t = threadIdx.x;
  const int base = t * 48;
  int s = 0;
#pragma unroll
  for (int i = 0; i < 48; ++i) s += cnt[base + i];
  ts[t] = s;
  __syncthreads();
  for (int d = 1; d < 256; d <<= 1) {
    int v = (t >= d) ? ts[t - d] : 0;
    __syncthreads();
    ts[t] += v;
    __syncthreads();
  }
  int run = (t == 0) ? 0 : ts[t - 1];
  for (int i = 0; i < 48; ++i) { head[base + i] = run; run += cnt[base + i]; }
}

__global__ void scatter_kernel(const int* __restrict__ recv, int* __restrict__ head,
                               int* __restrict__ perm) {
  int e = blockIdx.x * 256 + threadIdx.x;
  if (e < E_EDGES) {
    int pos = atomicAdd(&head[recv[e]], 1);
    perm[pos] = e;
  }
}

// Edge layer-1 over receiver-sorted edges. K padded to 160: cols 0..3 = edge_attr,
// 4..131 = x, 132 = 1.0 (bias row in w1sw), 133..159 = 0.
// As XOR-swizzled (byte ^= (row&7)<<4 in 128B windows) -> conflict-free b128 A-reads.
// Segmented reduce = indicator MFMA: S[s][n] = sum_r (seg[r]==s) * h[r][n].
__global__ __launch_bounds__(256, 4) void edge_kernel(
    const float* __restrict__ x, const float* __restrict__ edge_attr,
    const int* __restrict__ recv, const int* __restrict__ perm,
    const unsigned short* __restrict__ w1sw, float* __restrict__ s) {
  __shared__ __align__(16) char hsT[256 * 144];  // h transposed [col][k] bf16 stride 72; low 24576B aliases As[64][384B]
  __shared__ __align__(16) char indT[16 * 144];  // indicator [seg][k] bf16 stride 72
  __shared__ unsigned int seg32[16];             // seg id per row, u8-packed
  __shared__ int seg_recv[64];
  __shared__ int ev[64];
  __shared__ int rs[64];
  char* As = hsT;

  const int tid = threadIdx.x;
  const int l  = tid & 63;
  const int w  = tid >> 6;
  const int lo = l & 15, hi = l >> 4;
  const int p0 = blockIdx.x * 64;
  const int b  = blockIdx.y;

  if (tid < 64) {
    int e = perm[p0 + tid];
    ev[tid] = e;
    rs[tid] = recv[e];
  }
  // pad cols 132..159(+slack): col 132 = 1.0bf (bias input), rest 0; swizzled
  for (int idx = tid; idx < 960; idx += 256) {
    int r = idx / 15, k2 = idx - r * 15;
    int byte0 = 264 + 8 * k2;
    uint2 vz = make_uint2(k2 == 0 ? 0x00003F80u : 0u, 0u);
    *(uint2*)(As + r * 384 + (byte0 ^ ((r & 7) << 4))) = vz;
  }
  __syncthreads();

  // gather x rows (4 threads/row; i*4+q keeps each instr on whole 64B lines)
  {
    const int r = tid >> 2, q = tid & 3;
    const int e = ev[r];
    const int rx = (r & 7) << 4;
    const float4* xr = (const float4*)(x + ((size_t)b * E_EDGES + e) * DX);
#pragma unroll
    for (int i = 0; i < 8; ++i) {
      int t = i * 4 + q;
      float4 v = xr[t];
      int byte0 = 8 + 8 * t;
      *(uint2*)(As + r * 384 + (byte0 ^ rx)) = make_uint2(pk2(v.x, v.y), pk2(v.z, v.w));
    }
  }
  // segment metadata (segmask identical across waves)
  const int flag = (l == 63) || (rs[l + 1] != rs[l]);
  const unsigned long long segmask = __ballot(flag);
  const int nseg = __popcll(segmask);
  if (tid < 64) {
    float4 ea = *(const float4*)(edge_attr + (size_t)ev[tid] * 4);
    *(uint2*)(As + tid * 384 + ((tid & 7) << 4)) =
        make_uint2(pk2(ea.x, ea.y), pk2(ea.z, ea.w));
    int sid = __popcll(segmask & ((1ull << tid) - 1ull));
    ((unsigned char*)seg32)[tid] = (unsigned char)sid;
    if (flag) seg_recv[sid] = rs[tid];
  }
  __syncthreads();

  // indicator tile for pass 0 (only reads seg32; overlaps main MFMA phase)
  {
    int m = tid & 15, k4 = tid >> 4;
    unsigned four = seg32[k4];
    unsigned um = (unsigned)m;
    unsigned e0 = ((four & 255u) == um) ? 0x3F80u : 0u;
    unsigned e1 = (((four >> 8) & 255u) == um) ? 0x3F80u : 0u;
    unsigned e2 = (((four >> 16) & 255u) == um) ? 0x3F80u : 0u;
    unsigned e3 = ((four >> 24) == um) ? 0x3F80u : 0u;
    *(uint2*)(indT + m * 144 + k4 * 8) = make_uint2(e0 | (e1 << 16), e2 | (e3 << 16));
  }

  f32x4 acc[4][4] = {};
  const int axor = (lo & 7) << 4;  // row&7 == lo&7 since A rows are mf*16+lo
#pragma unroll
  for (int kk = 0; kk < 5; ++kk) {
    bf16x8 a[4], bb[4];
#pragma unroll
    for (int mf = 0; mf < 4; ++mf)
      a[mf] = *(const bf16x8*)(As + (mf * 16 + lo) * 384 + ((kk * 64 + hi * 16) ^ axor));
#pragma unroll
    for (int nf = 0; nf < 4; ++nf)
      bb[nf] = *(const bf16x8*)&w1sw[(size_t)(((kk * 16) + (w * 4 + nf)) * 64 + l) * 8];
#pragma unroll
    for (int mf = 0; mf < 4; ++mf)
#pragma unroll
      for (int nf = 0; nf < 4; ++nf)
        acc[mf][nf] = __builtin_amdgcn_mfma_f32_16x16x32_bf16(a[mf], bb[nf], acc[mf][nf], 0, 0, 0);
  }
  __syncthreads();  // As reads + indT writes complete

  // epilogue: silu -> hsT[col][k] (4 consecutive k per lane -> one b64 write)
#pragma unroll
  for (int mf = 0; mf < 4; ++mf) {
#pragma unroll
    for (int nf = 0; nf < 4; ++nf) {
      const int col = w * 64 + nf * 16 + lo;
      float v0 = silu_f(acc[mf][nf][0]);
      float v1 = silu_f(acc[mf][nf][1]);
      float v2 = silu_f(acc[mf][nf][2]);
      float v3 = silu_f(acc[mf][nf][3]);
      *(uint2*)(hsT + col * 144 + (mf * 16 + hi * 4) * 2) =
          make_uint2(pk2(v0, v1), pk2(v2, v3));
    }
  }
  __syncthreads();

  // segmented sum via indicator MFMA, 16 segments per pass (npass = 1 in practice)
  float* sb = s + (size_t)b * NRECV * 256;
  for (int p = 0;;) {
    f32x4 accS[4] = {};
#pragma unroll
    for (int kk = 0; kk < 2; ++kk) {
      bf16x8 a = *(const bf16x8*)(indT + lo * 144 + kk * 64 + hi * 16);
#pragma unroll
      for (int nf = 0; nf < 4; ++nf) {
        bf16x8 bb = *(const bf16x8*)(hsT + (w * 64 + nf * 16 + lo) * 144 + kk * 64 + hi * 16);
        accS[nf] = __builtin_amdgcn_mfma_f32_16x16x32_bf16(a, bb, accS[nf], 0, 0, 0);
      }
    }
#pragma unroll
    for (int j = 0; j < 4; ++j) {
      int sidx = p * 16 + hi * 4 + j;
      if (sidx < nseg) {
        int rcv = seg_recv[sidx];
#pragma unroll
        for (int nf = 0; nf < 4; ++nf)
          atomicAdd(sb + (size_t)rcv * 256 + w * 64 + nf * 16 + lo, accS[nf][j]);
      }
    }
    ++p;
    if (p * 16 >= nseg) break;   // nseg block-uniform -> no barrier divergence
    __syncthreads();
    {
      int m = tid & 15, k4 = tid >> 4;
      unsigned four = seg32[k4];
      unsigned um = (unsigned)(m + p * 16);
      unsigned e0 = ((four & 255u) == um) ? 0x3F80u : 0u;
      unsigned e1 = (((four >> 8) & 255u) == um) ? 0x3F80u : 0u;
      unsigned e2 = (((four >> 16) & 255u) == um) ? 0x3F80u : 0u;
      unsigned e3 = ((four >> 24) == um) ? 0x3F80u : 0u;
      *(uint2*)(indT + m * 144 + k4 * 8) = make_uint2(e0 | (e1 << 16), e2 | (e3 << 16));
    }
    __syncthreads();
  }
}

__device__ __forceinline__ void gemm64(const unsigned short* Ns,
                                       const unsigned short* __restrict__ Bsw,
                                       int w, int l, f32x4 acc[4][4]) {
  const int lo = l & 15, hi = l >> 4;
#pragma unroll
  for (int kk = 0; kk < 8; ++kk) {
    bf16x8 a[4], bb[4];
#pragma unroll
    for (int mf = 0; mf < 4; ++mf)
      a[mf] = *(const bf16x8*)&Ns[(mf * 16 + lo) * 264 + kk * 32 + hi * 8];
#pragma unroll
    for (int nf = 0; nf < 4; ++nf)
      bb[nf] = *(const bf16x8*)&Bsw[(size_t)(((kk * 16) + (w * 4 + nf)) * 64 + l) * 8];
#pragma unroll
    for (int mf = 0; mf < 4; ++mf)
#pragma unroll
      for (int nf = 0; nf < 4; ++nf)
        acc[mf][nf] = __builtin_amdgcn_mfma_f32_16x16x32_bf16(a[mf], bb[nf], acc[mf][nf], 0, 0, 0);
  }
}

// Node pass: vm = s@w2e + cnt*b2e; out = silu(vm@w1f + b1f)@w2f + b2f
__global__ __launch_bounds__(256) void node_kernel(
    const float* __restrict__ s, const int* __restrict__ cnt,
    const unsigned short* __restrict__ w2esw, const float* __restrict__ b2e,
    const unsigned short* __restrict__ w1fsw, const float* __restrict__ b1f,
    const unsigned short* __restrict__ w2fsw, const float* __restrict__ b2f,
    float* __restrict__ out) {
  __shared__ unsigned short Ns[64 * 264];
  __shared__ int   cntl[64];
  __shared__ float bias1[256], bias2[256], bias3[256];

  const int tid = threadIdx.x;
  const int l  = tid & 63;
  const int w  = tid >> 6;
  const int lo = l & 15, hi = l >> 4;
  const int r0 = blockIdx.x * 64;
  const int b  = blockIdx.y;

  const float4* sb = (const float4*)(s + ((size_t)b * NRECV + r0) * 256);
#pragma unroll
  for (int i = 0; i < 16; ++i) {
    int f = i * 256 + tid;
    float4 v = sb[f];
    int g = f * 4;
    int row = g >> 8, col = g & 255;
    *(uint2*)&Ns[row * 264 + col] = make_uint2(pk2(v.x, v.y), pk2(v.z, v.w));
  }
  if (tid < 64) cntl[tid] = cnt[r0 + tid];
  bias1[tid] = b2e[tid];
  bias2[tid] = b1f[tid];
  bias3[tid] = b2f[tid];
  __syncthreads();

  {
    f32x4 acc[4][4] = {};
    gemm64(Ns, w2esw, w, l, acc);
    __syncthreads();
#pragma unroll
    for (int mf = 0; mf < 4; ++mf)
#pragma unroll
      for (int nf = 0; nf < 4; ++nf) {
        const int col = w * 64 + nf * 16 + lo;
#pragma unroll
        for (int j = 0; j < 4; ++j) {
          const int row = mf * 16 + hi * 4 + j;
          float v = acc[mf][nf][j] + (float)cntl[row] * bias1[col];
          Ns[row * 264 + col] = f2bf(v);
        }
      }
    __syncthreads();
  }
  {
    f32x4 acc[4][4] = {};
    gemm64(Ns, w1fsw, w, l, acc);
    __syncthreads();
#pragma unroll
    for (int mf = 0; mf < 4; ++mf)
#pragma unroll
      for (int nf = 0; nf < 4; ++nf) {
        const int col = w * 64 + nf * 16 + lo;
#pragma unroll
        for (int j = 0; j < 4; ++j) {
          const int row = mf * 16 + hi * 4 + j;
          float v = silu_f(acc[mf][nf][j] + bias2[col]);
          Ns[row * 264 + col] = f2bf(v);
        }
      }
    __syncthreads();
  }
  {
    f32x4 acc[4][4] = {};
    gemm64(Ns, w2fsw, w, l, acc);
#pragma unroll
    for (int mf = 0; mf < 4; ++mf)
#pragma unroll
      for (int nf = 0; nf < 4; ++nf) {
        const int col = w * 64 + nf * 16 + lo;
#pragma unroll
        for (int j = 0; j < 4; ++j) {
          const int row = mf * 16 + hi * 4 + j;
          out[((size_t)b * NRECV + r0 + row) * 256 + col] = acc[mf][nf][j] + bias3[col];
        }
      }
  }
}

extern "C" void kernel_launch(void* const* d_in, const int* in_sizes, int n_in,
                              void* d_out, int out_size, void* d_ws, size_t ws_size,
                              hipStream_t stream) {
  const float* x         = (const float*)d_in[0];
  const float* edge_attr = (const float*)d_in[1];
  const int*   edge_idx  = (const int*)d_in[2];
  const float* w1e       = (const float*)d_in[3];
  const float* b1e       = (const float*)d_in[4];
  const float* w2e       = (const float*)d_in[5];
  const float* b2e       = (const float*)d_in[6];
  const float* w1f       = (const float*)d_in[7];
  const float* b1f       = (const float*)d_in[8];
  const float* w2f       = (const float*)d_in[9];
  const float* b2f       = (const float*)d_in[10];
  float* out = (float*)d_out;

  char* ws = (char*)d_ws;
  float*          sbuf  = (float*)(ws + 0);                    // 25165824
  int*            cnt   = (int*)(ws + 25165824);               // 49152
  int*            head  = (int*)(ws + 25214976);               // 49152
  int*            perm  = (int*)(ws + 25264128);               // 1572864
  unsigned short* w1sw  = (unsigned short*)(ws + 26836992);    // 160*256*2 = 81920
  unsigned short* w2esw = (unsigned short*)(ws + 26918912);    // 131072
  unsigned short* w1fsw = (unsigned short*)(ws + 27049984);    // 131072
  unsigned short* w2fsw = (unsigned short*)(ws + 27181056);    // 131072

  // zero s + cnt (25214976 B = 1575936 float4s)
  zero_kernel<<<2048, 256, 0, stream>>>((float4*)ws, 1575936);

  swz_w1e_kernel<<<160, 256, 0, stream>>>(w1e, b1e, w1sw);
  swz_kernel<<<(256 * 256) / 256, 256, 0, stream>>>(w2e, w2esw, 256, 256);
  swz_kernel<<<(256 * 256) / 256, 256, 0, stream>>>(w1f, w1fsw, 256, 256);
  swz_kernel<<<(256 * 256) / 256, 256, 0, stream>>>(w2f, w2fsw, 256, 256);

  const int* recv = edge_idx + E_EDGES;  // edge_index[1]
  hist_kernel<<<E_EDGES / 256, 256, 0, stream>>>(recv, cnt);
  scan_kernel<<<1, 256, 0, stream>>>(cnt, head);
  scatter_kernel<<<E_EDGES / 256, 256, 0, stream>>>(recv, head, perm);

  dim3 eg(E_EDGES / 64, BATCH);
  edge_kernel<<<eg, 256, 0, stream>>>(x, edge_attr, recv, perm, w1sw, sbuf);

  dim3 ng(NRECV / 64, BATCH);
  node_kernel<<<ng, 256, 0, stream>>>(sbuf, cnt, w2esw, b2e, w1fsw, b1f, w2fsw, b2f, out);
}

// Round 6
// 250.265 us; speedup vs baseline: 2.8082x; 1.1134x over previous
//
#include <hip/hip_runtime.h>
#include <hip/hip_bf16.h>

#define E_EDGES 393216
#define NRECV   12288
#define DX      128
#define BATCH   2

typedef short bf16x8 __attribute__((ext_vector_type(8)));
typedef float f32x4  __attribute__((ext_vector_type(4)));

__device__ __forceinline__ unsigned short f2bf(float f) {
  union { float f; unsigned u; } v; v.f = f;
  unsigned r = v.u + 0x7FFFu + ((v.u >> 16) & 1u);  // RNE
  return (unsigned short)(r >> 16);
}

__device__ __forceinline__ unsigned pk2(float a, float b) {
  __hip_bfloat162 h = __float22bfloat162_rn(make_float2(a, b));
  union { __hip_bfloat162 h; unsigned u; } c; c.h = h;
  return c.u;
}

__device__ __forceinline__ float silu_f(float v) {
  // v * rcp(1 + exp(-v)); v_exp_f32 + v_rcp_f32, error << bf16 rounding
  float e = __builtin_amdgcn_exp2f(v * -1.44269504089f);
  return v * __builtin_amdgcn_rcpf(1.0f + e);
}

// fast zero fill: n float4s, grid-stride
__global__ __launch_bounds__(256) void zero_kernel(float4* __restrict__ p, int n4) {
  int i = blockIdx.x * 256 + threadIdx.x;
  int stride = gridDim.x * 256;
  float4 z = make_float4(0.f, 0.f, 0.f, 0.f);
  for (; i < n4; i += stride) p[i] = z;
}

// All weight pre-swizzles in one launch.
// blocks 0..159: w1e padded K132->160 (row132 = b1e); blocks 160..927: three 256x256 mats.
__global__ __launch_bounds__(256) void swz_all_kernel(
    const float* __restrict__ w1e, const float* __restrict__ b1e,
    const float* __restrict__ w2e, const float* __restrict__ w1f,
    const float* __restrict__ w2f,
    unsigned short* __restrict__ w1sw, unsigned short* __restrict__ w2esw,
    unsigned short* __restrict__ w1fsw, unsigned short* __restrict__ w2fsw) {
  int blk = blockIdx.x;
  if (blk < 160) {
    int t = blk * 256 + threadIdx.x;  // 0..40959
    int j = t & 7, l = (t >> 3) & 63, rest = t >> 9;
    int nf = rest & 15, ks = rest >> 4;
    int k = ks * 32 + (l >> 4) * 8 + j;
    int n = nf * 16 + (l & 15);
    float v = (k < 132) ? w1e[k * 256 + n] : (k == 132 ? b1e[n] : 0.0f);
    w1sw[t] = f2bf(v);
  } else {
    int g = blk - 160;
    int which = g >> 8;
    int t = (g & 255) * 256 + threadIdx.x;  // 0..65535
    const float* W = (which == 0) ? w2e : (which == 1) ? w1f : w2f;
    unsigned short* O = (which == 0) ? w2esw : (which == 1) ? w1fsw : w2fsw;
    int j = t & 7, l = (t >> 3) & 63, rest = t >> 9;
    int nf = rest & 15, ks = rest >> 4;
    int k = ks * 32 + (l >> 4) * 8 + j;
    int n = nf * 16 + (l & 15);
    O[t] = f2bf(W[k * 256 + n]);
  }
}

__global__ void hist_kernel(const int* __restrict__ recv, int* __restrict__ cnt) {
  int e = blockIdx.x * 256 + threadIdx.x;
  if (e < E_EDGES) atomicAdd(&cnt[recv[e]], 1);
}

// exclusive prefix of cnt[12288] -> head[12288]; single block of 256
__global__ __launch_bounds__(256) void scan_kernel(const int* __restrict__ cnt,
                                                   int* __restrict__ head) {
  __shared__ int ts[256];
  const int t = threadIdx.x;
  const int base = t * 48;
  int s = 0;
#pragma unroll
  for (int i = 0; i < 48; ++i) s += cnt[base + i];
  ts[t] = s;
  __syncthreads();
  for (int d = 1; d < 256; d <<= 1) {
    int v = (t >= d) ? ts[t - d] : 0;
    __syncthreads();
    ts[t] += v;
    __syncthreads();
  }
  int run = (t == 0) ? 0 : ts[t - 1];
  for (int i = 0; i < 48; ++i) { head[base + i] = run; run += cnt[base + i]; }
}

__global__ void scatter_kernel(const int* __restrict__ recv, int* __restrict__ head,
                               int* __restrict__ perm) {
  int e = blockIdx.x * 256 + threadIdx.x;
  if (e < E_EDGES) {
    int pos = atomicAdd(&head[recv[e]], 1);
    perm[pos] = e;
  }
}

// Edge layer-1 over receiver-sorted edges. K padded to 160: cols 0..3 = edge_attr,
// 4..131 = x, 132 = 1.0 (bias row folded into w1sw), 133..159 = 0.
// As XOR-swizzled (byte ^= (row&7)<<4 in 128B windows) -> ~2-way max on b128 A-reads.
// h never leaves registers: segment-sum B-frags built by cross-lane shuffles,
// indicator A-frags built in-register from packed u8 seg ids; S = I^T @ h via MFMA.
__global__ __launch_bounds__(256, 4) void edge_kernel(
    const float* __restrict__ x, const float* __restrict__ edge_attr,
    const int* __restrict__ recv, const int* __restrict__ perm,
    const unsigned short* __restrict__ w1sw, float* __restrict__ s) {
  __shared__ __align__(16) char As[64 * 384];  // 24576 B
  __shared__ int rs[64];
  __shared__ int seg_recv[64];
  __shared__ unsigned seg32[16];               // u8 seg id per row

  const int tid = threadIdx.x;
  const int l  = tid & 63;
  const int w  = tid >> 6;
  const int lo = l & 15, hi = l >> 4;
  const int p0 = blockIdx.x * 64;
  const int b  = blockIdx.y;

  // ---- issue gather loads FIRST (no LDS dependency) ----
  const int r = tid >> 2, q = tid & 3;
  const int er = perm[p0 + r];
  const float4* xr = (const float4*)(x + ((size_t)b * E_EDGES + er) * DX);
  float4 xv[8];
#pragma unroll
  for (int i = 0; i < 8; ++i) xv[i] = xr[i * 4 + q];  // i*4+q: whole 64B lines per instr

  float4 ea;
  if (tid < 64) {
    int e1 = perm[p0 + tid];
    rs[tid] = recv[e1];
    ea = *(const float4*)(edge_attr + (size_t)e1 * 4);
  }

  // pad cols 132..191: col 132 = 1.0bf (bias input), rest 0; swizzled
  for (int idx = tid; idx < 960; idx += 256) {
    int rr = idx / 15, k2 = idx - rr * 15;
    int byte0 = 264 + 8 * k2;
    uint2 vz = make_uint2(k2 == 0 ? 0x00003F80u : 0u, 0u);
    *(uint2*)(As + rr * 384 + (byte0 ^ ((rr & 7) << 4))) = vz;
  }

  // write gathered x -> swizzled bf16 As
  {
    const int rx = (r & 7) << 4;
#pragma unroll
    for (int i = 0; i < 8; ++i) {
      int t = i * 4 + q;
      int byte0 = 8 + 8 * t;
      *(uint2*)(As + r * 384 + (byte0 ^ rx)) =
          make_uint2(pk2(xv[i].x, xv[i].y), pk2(xv[i].z, xv[i].w));
    }
  }
  if (tid < 64) {
    *(uint2*)(As + tid * 384 + ((tid & 7) << 4)) =
        make_uint2(pk2(ea.x, ea.y), pk2(ea.z, ea.w));
  }
  __syncthreads();

  // segment metadata: per-wave ballot (identical across waves); wave0 publishes ids
  const int flag = (l == 63) || (rs[l + 1] != rs[l]);
  const unsigned long long segmask = __ballot(flag);
  const int nseg = __popcll(segmask);
  if (tid < 64) {
    int sid = __popcll(segmask & ((1ull << tid) - 1ull));
    ((unsigned char*)seg32)[tid] = (unsigned char)sid;
    if (flag) seg_recv[sid] = rs[tid];
  }

  // ---- main MFMA: h = silu-input tile, acc[mf][nf] rows=edges cols=hidden ----
  f32x4 acc[4][4] = {};
  const int axor = (lo & 7) << 4;  // A-row & 7 == lo & 7 since rows are mf*16+lo
#pragma unroll
  for (int kk = 0; kk < 5; ++kk) {
    bf16x8 a[4], bb[4];
#pragma unroll
    for (int mf = 0; mf < 4; ++mf)
      a[mf] = *(const bf16x8*)(As + (mf * 16 + lo) * 384 + ((kk * 64 + hi * 16) ^ axor));
#pragma unroll
    for (int nf = 0; nf < 4; ++nf)
      bb[nf] = *(const bf16x8*)&w1sw[(size_t)(((kk * 16) + (w * 4 + nf)) * 64 + l) * 8];
#pragma unroll
    for (int mf = 0; mf < 4; ++mf)
#pragma unroll
      for (int nf = 0; nf < 4; ++nf)
        acc[mf][nf] = __builtin_amdgcn_mfma_f32_16x16x32_bf16(a[mf], bb[nf], acc[mf][nf], 0, 0, 0);
  }
  __syncthreads();  // seg32/seg_recv visible to all waves

  // ---- silu + pack to bf16 pairs (row pairs (0,1),(2,3) per fragment) ----
  unsigned pkd[4][4][2];
#pragma unroll
  for (int mf = 0; mf < 4; ++mf)
#pragma unroll
    for (int nf = 0; nf < 4; ++nf) {
      float v0 = silu_f(acc[mf][nf][0]);
      float v1 = silu_f(acc[mf][nf][1]);
      float v2 = silu_f(acc[mf][nf][2]);
      float v3 = silu_f(acc[mf][nf][3]);
      pkd[mf][nf][0] = pk2(v0, v1);
      pkd[mf][nf][1] = pk2(v2, v3);
    }

  // ---- build segment-MFMA B-frags in-register via shuffles ----
  // dest lane (hi,lo) dword t of frag (kk,nf) = h[e=kk*32+hi*8+2t..+1][c=w*64+nf*16+lo]
  // src lane = ((hi&1)*2 + (t>>1))*16 + lo; mf = 2kk + (hi>>1); pair idx = t&1
  unsigned hbw[2][4][4];
#pragma unroll
  for (int kk = 0; kk < 2; ++kk)
#pragma unroll
    for (int nf = 0; nf < 4; ++nf)
#pragma unroll
      for (int t = 0; t < 4; ++t) {
        int src = ((hi & 1) * 2 + (t >> 1)) * 16 + lo;
        int a0 = __shfl((int)pkd[2 * kk][nf][t & 1], src, 64);
        int a1 = __shfl((int)pkd[2 * kk + 1][nf][t & 1], src, 64);
        hbw[kk][nf][t] = (hi & 2) ? (unsigned)a1 : (unsigned)a0;
      }

  // ---- segmented sum S = I^T @ h via indicator MFMA; 16 segs/pass ----
  float* sb = s + (size_t)b * NRECV * 256;
  for (int p = 0; p * 16 < nseg; ++p) {
    union { unsigned u[4]; bf16x8 v; } ia[2];
#pragma unroll
    for (int kk = 0; kk < 2; ++kk) {
      unsigned d0 = seg32[kk * 8 + hi * 2];
      unsigned d1 = seg32[kk * 8 + hi * 2 + 1];
      unsigned tgt = (unsigned)(lo + p * 16);
      ia[kk].u[0] = (((d0 & 255u) == tgt) ? 0x3F80u : 0u) |
                    ((((d0 >> 8) & 255u) == tgt) ? 0x3F800000u : 0u);
      ia[kk].u[1] = ((((d0 >> 16) & 255u) == tgt) ? 0x3F80u : 0u) |
                    (((d0 >> 24) == tgt) ? 0x3F800000u : 0u);
      ia[kk].u[2] = (((d1 & 255u) == tgt) ? 0x3F80u : 0u) |
                    ((((d1 >> 8) & 255u) == tgt) ? 0x3F800000u : 0u);
      ia[kk].u[3] = ((((d1 >> 16) & 255u) == tgt) ? 0x3F80u : 0u) |
                    (((d1 >> 24) == tgt) ? 0x3F800000u : 0u);
    }
    f32x4 accS[4] = {};
#pragma unroll
    for (int kk = 0; kk < 2; ++kk)
#pragma unroll
      for (int nf = 0; nf < 4; ++nf) {
        union { unsigned u[4]; bf16x8 v; } hb;
        hb.u[0] = hbw[kk][nf][0]; hb.u[1] = hbw[kk][nf][1];
        hb.u[2] = hbw[kk][nf][2]; hb.u[3] = hbw[kk][nf][3];
        accS[nf] = __builtin_amdgcn_mfma_f32_16x16x32_bf16(ia[kk].v, hb.v, accS[nf], 0, 0, 0);
      }
#pragma unroll
    for (int j = 0; j < 4; ++j) {
      int sidx = p * 16 + hi * 4 + j;
      if (sidx < nseg) {
        int rcv = seg_recv[sidx];
#pragma unroll
        for (int nf = 0; nf < 4; ++nf)
          atomicAdd(sb + (size_t)rcv * 256 + w * 64 + nf * 16 + lo, accS[nf][j]);
      }
    }
  }
}

__device__ __forceinline__ void gemm64(const unsigned short* Ns,
                                       const unsigned short* __restrict__ Bsw,
                                       int w, int l, f32x4 acc[4][4]) {
  const int lo = l & 15, hi = l >> 4;
#pragma unroll
  for (int kk = 0; kk < 8; ++kk) {
    bf16x8 a[4], bb[4];
#pragma unroll
    for (int mf = 0; mf < 4; ++mf)
      a[mf] = *(const bf16x8*)&Ns[(mf * 16 + lo) * 264 + kk * 32 + hi * 8];
#pragma unroll
    for (int nf = 0; nf < 4; ++nf)
      bb[nf] = *(const bf16x8*)&Bsw[(size_t)(((kk * 16) + (w * 4 + nf)) * 64 + l) * 8];
#pragma unroll
    for (int mf = 0; mf < 4; ++mf)
#pragma unroll
      for (int nf = 0; nf < 4; ++nf)
        acc[mf][nf] = __builtin_amdgcn_mfma_f32_16x16x32_bf16(a[mf], bb[nf], acc[mf][nf], 0, 0, 0);
  }
}

// Node pass: vm = s@w2e + cnt*b2e; out = silu(vm@w1f + b1f)@w2f + b2f
__global__ __launch_bounds__(256) void node_kernel(
    const float* __restrict__ s, const int* __restrict__ cnt,
    const unsigned short* __restrict__ w2esw, const float* __restrict__ b2e,
    const unsigned short* __restrict__ w1fsw, const float* __restrict__ b1f,
    const unsigned short* __restrict__ w2fsw, const float* __restrict__ b2f,
    float* __restrict__ out) {
  __shared__ unsigned short Ns[64 * 264];
  __shared__ int   cntl[64];
  __shared__ float bias1[256], bias2[256], bias3[256];

  const int tid = threadIdx.x;
  const int l  = tid & 63;
  const int w  = tid >> 6;
  const int lo = l & 15, hi = l >> 4;
  const int r0 = blockIdx.x * 64;
  const int b  = blockIdx.y;

  const float4* sb = (const float4*)(s + ((size_t)b * NRECV + r0) * 256);
#pragma unroll
  for (int i = 0; i < 16; ++i) {
    int f = i * 256 + tid;
    float4 v = sb[f];
    int g = f * 4;
    int row = g >> 8, col = g & 255;
    *(uint2*)&Ns[row * 264 + col] = make_uint2(pk2(v.x, v.y), pk2(v.z, v.w));
  }
  if (tid < 64) cntl[tid] = cnt[r0 + tid];
  bias1[tid] = b2e[tid];
  bias2[tid] = b1f[tid];
  bias3[tid] = b2f[tid];
  __syncthreads();

  {
    f32x4 acc[4][4] = {};
    gemm64(Ns, w2esw, w, l, acc);
    __syncthreads();
#pragma unroll
    for (int mf = 0; mf < 4; ++mf)
#pragma unroll
      for (int nf = 0; nf < 4; ++nf) {
        const int col = w * 64 + nf * 16 + lo;
#pragma unroll
        for (int j = 0; j < 4; ++j) {
          const int row = mf * 16 + hi * 4 + j;
          float v = acc[mf][nf][j] + (float)cntl[row] * bias1[col];
          Ns[row * 264 + col] = f2bf(v);
        }
      }
    __syncthreads();
  }
  {
    f32x4 acc[4][4] = {};
    gemm64(Ns, w1fsw, w, l, acc);
    __syncthreads();
#pragma unroll
    for (int mf = 0; mf < 4; ++mf)
#pragma unroll
      for (int nf = 0; nf < 4; ++nf) {
        const int col = w * 64 + nf * 16 + lo;
#pragma unroll
        for (int j = 0; j < 4; ++j) {
          const int row = mf * 16 + hi * 4 + j;
          float v = silu_f(acc[mf][nf][j] + bias2[col]);
          Ns[row * 264 + col] = f2bf(v);
        }
      }
    __syncthreads();
  }
  {
    f32x4 acc[4][4] = {};
    gemm64(Ns, w2fsw, w, l, acc);
#pragma unroll
    for (int mf = 0; mf < 4; ++mf)
#pragma unroll
      for (int nf = 0; nf < 4; ++nf) {
        const int col = w * 64 + nf * 16 + lo;
#pragma unroll
        for (int j = 0; j < 4; ++j) {
          const int row = mf * 16 + hi * 4 + j;
          out[((size_t)b * NRECV + r0 + row) * 256 + col] = acc[mf][nf][j] + bias3[col];
        }
      }
  }
}

extern "C" void kernel_launch(void* const* d_in, const int* in_sizes, int n_in,
                              void* d_out, int out_size, void* d_ws, size_t ws_size,
                              hipStream_t stream) {
  const float* x         = (const float*)d_in[0];
  const float* edge_attr = (const float*)d_in[1];
  const int*   edge_idx  = (const int*)d_in[2];
  const float* w1e       = (const float*)d_in[3];
  const float* b1e       = (const float*)d_in[4];
  const float* w2e       = (const float*)d_in[5];
  const float* b2e       = (const float*)d_in[6];
  const float* w1f       = (const float*)d_in[7];
  const float* b1f       = (const float*)d_in[8];
  const float* w2f       = (const float*)d_in[9];
  const float* b2f       = (const float*)d_in[10];
  float* out = (float*)d_out;

  char* ws = (char*)d_ws;
  float*          sbuf  = (float*)(ws + 0);                    // 25165824
  int*            cnt   = (int*)(ws + 25165824);               // 49152
  int*            head  = (int*)(ws + 25214976);               // 49152
  int*            perm  = (int*)(ws + 25264128);               // 1572864
  unsigned short* w1sw  = (unsigned short*)(ws + 26836992);    // 160*256*2 = 81920
  unsigned short* w2esw = (unsigned short*)(ws + 26918912);    // 131072
  unsigned short* w1fsw = (unsigned short*)(ws + 27049984);    // 131072
  unsigned short* w2fsw = (unsigned short*)(ws + 27181056);    // 131072

  // zero s + cnt (25214976 B = 1575936 float4s)
  zero_kernel<<<2048, 256, 0, stream>>>((float4*)ws, 1575936);

  swz_all_kernel<<<928, 256, 0, stream>>>(w1e, b1e, w2e, w1f, w2f,
                                          w1sw, w2esw, w1fsw, w2fsw);

  const int* recv = edge_idx + E_EDGES;  // edge_index[1]
  hist_kernel<<<E_EDGES / 256, 256, 0, stream>>>(recv, cnt);
  scan_kernel<<<1, 256, 0, stream>>>(cnt, head);
  scatter_kernel<<<E_EDGES / 256, 256, 0, stream>>>(recv, head, perm);

  dim3 eg(E_EDGES / 64, BATCH);
  edge_kernel<<<eg, 256, 0, stream>>>(x, edge_attr, recv, perm, w1sw, sbuf);

  dim3 ng(NRECV / 64, BATCH);
  node_kernel<<<ng, 256, 0, stream>>>(sbuf, cnt, w2esw, b2e, w1fsw, b1f, w2fsw, b2f, out);
}